// Round 8
// baseline (101.129 us; speedup 1.0000x reference)
//
#include <hip/hip_runtime.h>
#include <hip/hip_bf16.h>
#include <math.h>

#define NN 2048
#define CC 256
#define KK 16
#define SS 128
#define HH 8
#define DH 64
#define INNER 512

using short8 = __attribute__((ext_vector_type(8))) short;
using f32x4  = __attribute__((ext_vector_type(4))) float;
typedef __hip_bfloat16 bf16;

__device__ __forceinline__ short f2bf(float f) {
  bf16 b = __float2bfloat16(f);
  short s; __builtin_memcpy(&s, &b, 2); return s;
}
__device__ __forceinline__ float bf2f(short s) {
  unsigned u = ((unsigned)(unsigned short)s) << 16;
  float f; __builtin_memcpy(&f, &u, 4); return f;
}

// ---------------- helpers ----------------

__device__ __forceinline__ void block_reduce2(float v1, float v2, float* red, float& o1, float& o2) {
  #pragma unroll
  for (int o = 32; o > 0; o >>= 1) { v1 += __shfl_xor(v1, o, 64); v2 += __shfl_xor(v2, o, 64); }
  __syncthreads();
  int wid = threadIdx.x >> 6;
  if ((threadIdx.x & 63) == 0) { red[wid] = v1; red[4 + wid] = v2; }
  __syncthreads();
  o1 = red[0] + red[1] + red[2] + red[3];
  o2 = red[4] + red[5] + red[6] + red[7];
}

// ---------------- prep + LN1 ----------------
// BLOCK MAP (grid 2368):
//   [0,8)      node->cluster/pos maps
//   [8,40)     zero adjb: 32 blocks x 256 = 8192 words = 32KB (EXACTLY adjb's size)
//   [40,42)    e01
//   [42,58)    rope table [128][32] float2
//   [58,64)    bqkv concat [1536]
//   [64,320)   weight transposes, 256 blocks of 64x64 f32 tiles via LDS:
//              [64,96) Wq  [96,160) Wkv  [160,192) Wo  [192,256) W1  [256,320) W2
//   [320,2368) LN1: row = b - 320

#define LNB 320

__global__ __launch_bounds__(256) void prep_ln(const int* __restrict__ clusters,
    const float* __restrict__ adj_emb, const float* __restrict__ We, const float* __restrict__ be,
    const float* __restrict__ Wq, const float* __restrict__ Wkv, const float* __restrict__ Wo,
    const float* __restrict__ W1, const float* __restrict__ W2,
    const float* __restrict__ bq, const float* __restrict__ bkv,
    const float* __restrict__ x, const float* __restrict__ ln1_g, const float* __restrict__ ln1_b,
    int* __restrict__ node2c, int* __restrict__ node2p, unsigned* __restrict__ adjb,
    float* __restrict__ e01, float2* __restrict__ rope, float* __restrict__ bqkv,
    bf16* __restrict__ Wqkvt, bf16* __restrict__ Wot, bf16* __restrict__ W1t,
    bf16* __restrict__ W2t, bf16* __restrict__ h) {
  __shared__ float red[8];
  __shared__ float tile[64][65];
  int b = blockIdx.x, tid = threadIdx.x;
  if (b >= LNB) {                                // LN1 (gathered)
    int row = b - LNB;
    int node = clusters[row];
    float v = x[(size_t)node * CC + tid];
    float s, s2;
    block_reduce2(v, v * v, red, s, s2);
    float m = s * (1.f / CC);
    float var = s2 * (1.f / CC) - m * m;
    float r = rsqrtf(var + 1e-5f);
    h[(size_t)row * CC + tid] = __float2bfloat16((v - m) * r * ln1_g[tid] + ln1_b[tid]);
    return;
  }
  if (b >= 64) {                                 // weight transpose tiles
    int t = b - 64;
    const float* src; bf16* dst; int srcN, dstK, k0, n0;
    if (t < 32)       { src = Wq;  dst = Wqkvt;             srcN = 512;  dstK = 256;
                        k0 = (t & 3) * 64;        n0 = (t >> 2) * 64; }
    else if (t < 96)  { int u = t - 32;  src = Wkv; dst = Wqkvt + 512 * 256; srcN = 1024; dstK = 256;
                        k0 = (u & 3) * 64;        n0 = (u >> 2) * 64; }
    else if (t < 128) { int u = t - 96;  src = Wo;  dst = Wot; srcN = 256;  dstK = 512;
                        k0 = (u & 7) * 64;        n0 = (u >> 3) * 64; }
    else if (t < 192) { int u = t - 128; src = W1;  dst = W1t; srcN = 1024; dstK = 256;
                        k0 = (u & 3) * 64;        n0 = (u >> 2) * 64; }
    else              { int u = t - 192; src = W2;  dst = W2t; srcN = 256;  dstK = 1024;
                        k0 = (u & 15) * 64;       n0 = (u >> 4) * 64; }
    int rl = tid >> 6, cl = tid & 63;
    #pragma unroll
    for (int it = 0; it < 16; ++it) {
      int r = it * 4 + rl;
      tile[r][cl] = src[(size_t)(k0 + r) * srcN + n0 + cl];
    }
    __syncthreads();
    #pragma unroll
    for (int it = 0; it < 16; ++it) {
      int n = it * 4 + rl;
      dst[(size_t)(n0 + n) * dstK + k0 + cl] = __float2bfloat16(tile[cl][n]);
    }
    return;
  }
  if (b < 8) {                                   // node->cluster/pos maps
    int r = b * 256 + tid;
    int node = clusters[r];
    node2c[node] = r >> 7;
    node2p[node] = r & 127;
  } else if (b < 40) {                           // zero adjacency bitmask: 8192 words total
    adjb[(b - 8) * 256 + tid] = 0u;
  } else if (b < 42) {                           // e0/e1 = adj_emb @ We + be
    int j = (b - 40) * 256 + tid;
    float a0 = 0.f, a1 = 0.f;
    for (int c = 0; c < CC; ++c) {
      float w = We[(size_t)c * INNER + j];
      a0 = fmaf(adj_emb[c], w, a0);
      a1 = fmaf(adj_emb[CC + c], w, a1);
    }
    e01[j] = a0 + be[j];
    e01[INNER + j] = a1 + be[j];
  } else if (b < 58) {                           // rope table [128][32] (cos, sin)
    int idx = (b - 42) * 256 + tid;
    int s = idx >> 5, t = idx & 31;
    float ang = (float)s * exp2f(-(float)t * 0.41524101186092029f);  // s * 10000^(-t/32)
    float sn, cs;
    sincosf(ang, &sn, &cs);
    rope[idx] = make_float2(cs, sn);
  } else {                                       // bias concat [1536]
    int idx = (b - 58) * 256 + tid;
    bqkv[idx] = idx < 512 ? bq[idx] : bkv[idx - 512];
  }
}

__global__ void build_adj(const int* __restrict__ ei, const int* __restrict__ node2c,
                          const int* __restrict__ node2p, unsigned* __restrict__ adj, int E) {
  int t = blockIdx.x * 256 + threadIdx.x;
  if (t >= E) return;
  int u = ei[t], v = ei[E + t];
  int cu = node2c[u];
  if (cu == node2c[v]) {
    int pu = node2p[u], pv = node2p[v];
    atomicOr(&adj[(cu * 128 + pu) * 4 + (pv >> 5)], 1u << (pv & 31));
  }
}

// ---------------- fused QKV GEMM + rotary + attention ----------------
// 128 blocks = (cluster c = blk>>3, head hh = blk&7), 512 threads = 8 waves.
// Wave w owns rows [16w,16w+16): computes q/k/v via MFMA (A from global h),
// rotary in epilogue, q/k -> LDS (pitch 72), v -> LDS transposed; then the
// attention body (QK^T, softmax with adjacency e-bias, PV, epilogue).
// P-buffer unions with q_lds (q is dead after QK^T; barrier guards overlap).

__global__ __launch_bounds__(512) void qkv_attn(const bf16* __restrict__ h,
    const bf16* __restrict__ Wqkvt, const float* __restrict__ bqkv,
    const unsigned* __restrict__ adjb, const float* __restrict__ e01,
    const float2* __restrict__ rope, bf16* __restrict__ attn_o) {
  __shared__ union { short q[SS][72]; short P[8][16][136]; } uq;  // 34816 B
  __shared__ short Kb[SS][72];        // 18432 B
  __shared__ short Vt[DH][136];       // 17408 B
  __shared__ unsigned adjsh[SS][4];
  __shared__ float e0sh[DH], e1sh[DH];

  int c = blockIdx.x >> 3, hh = blockIdx.x & 7;
  int tid = threadIdx.x;
  int w = tid >> 6, l = tid & 63;
  int lg = l >> 4, lr = l & 15;
  int r0 = w * 16;

  if (tid < 128) {
    *(uint4*)&adjsh[tid][0] = *(const uint4*)(adjb + (size_t)(c * SS + tid) * 4);
  } else if (tid < 192) {
    e0sh[tid - 128] = e01[hh * DH + (tid - 128)];
  } else if (tid < 256) {
    e1sh[tid - 192] = e01[INNER + hh * DH + (tid - 192)];
  }

  // ---- QKV GEMM: 16 rows x 192 cols (q64|k64|v64 of head hh) ----
  const bf16* pa = h + ((size_t)(c * SS + r0 + lr)) * CC + lg * 8;
  short8 afr[8];
  #pragma unroll
  for (int kb = 0; kb < 8; ++kb) afr[kb] = *(const short8*)(pa + kb * 32);
  f32x4 acc[12];
  #pragma unroll
  for (int nf = 0; nf < 12; ++nf) acc[nf] = (f32x4){0.f, 0.f, 0.f, 0.f};
  #pragma unroll
  for (int nf = 0; nf < 12; ++nf) {
    int nbase = (nf >> 2) * 512 + hh * 64 + 16 * (nf & 3);
    const bf16* pbv = Wqkvt + (size_t)(nbase + lr) * CC + lg * 8;
    #pragma unroll
    for (int kb = 0; kb < 8; ++kb) {
      short8 bfr = *(const short8*)(pbv + kb * 32);
      acc[nf] = __builtin_amdgcn_mfma_f32_16x16x32_bf16(afr[kb], bfr, acc[nf], 0, 0, 0);
    }
  }
  // epilogue: bias + rotary(q,k) / transpose-store(v)
  #pragma unroll
  for (int nf = 0; nf < 12; ++nf) {
    int seg = nf >> 2;
    int nbase = seg * 512 + hh * 64 + 16 * (nf & 3);
    float bb = bqkv[nbase + lr];
    #pragma unroll
    for (int i = 0; i < 4; ++i) {
      float v = acc[nf][i] + bb;
      int row = r0 + 4 * lg + i;           // seq pos within cluster
      int col = 16 * (nf & 3) + lr;        // 0..63 head-local
      if (seg < 2) {
        float p = __shfl_xor(v, 1, 64);    // partner col^1 (lane^1, same frag)
        float2 cssn = rope[row * 32 + (col >> 1)];
        float o = (col & 1) ? fmaf(v, cssn.x, p * cssn.y) : fmaf(v, cssn.x, -p * cssn.y);
        if (seg == 0) uq.q[row][col] = f2bf(o);
        else          Kb[row][col]   = f2bf(o);
      } else {
        Vt[col][row] = f2bf(v);
      }
    }
  }
  __syncthreads();

  // ---- Q frags + qe dots (rows r0+lr) ----
  short8 aq0 = *(const short8*)&uq.q[r0 + lr][lg * 8];
  short8 aq1 = *(const short8*)&uq.q[r0 + lr][lg * 8 + 32];
  float d0 = 0.f, d1 = 0.f;
  #pragma unroll
  for (int e = 0; e < 8; ++e) {
    float q0 = bf2f(aq0[e]), q1 = bf2f(aq1[e]);
    d0 += q0 * e0sh[lg * 8 + e] + q1 * e0sh[lg * 8 + 32 + e];
    d1 += q0 * e1sh[lg * 8 + e] + q1 * e1sh[lg * 8 + 32 + e];
  }
  d0 += __shfl_xor(d0, 16, 64); d0 += __shfl_xor(d0, 32, 64);
  d1 += __shfl_xor(d1, 16, 64); d1 += __shfl_xor(d1, 32, 64);

  // ---- QK^T ----
  f32x4 sacc[8];
  #pragma unroll
  for (int n = 0; n < 8; ++n) sacc[n] = (f32x4){0.f, 0.f, 0.f, 0.f};
  #pragma unroll
  for (int n = 0; n < 8; ++n) {
    short8 bk0 = *(const short8*)&Kb[16 * n + lr][lg * 8];
    short8 bk1 = *(const short8*)&Kb[16 * n + lr][lg * 8 + 32];
    sacc[n] = __builtin_amdgcn_mfma_f32_16x16x32_bf16(aq0, bk0, sacc[n], 0, 0, 0);
    sacc[n] = __builtin_amdgcn_mfma_f32_16x16x32_bf16(aq1, bk1, sacc[n], 0, 0, 0);
  }
  __syncthreads();   // all q_lds reads complete before P overwrites the union

  // ---- softmax on C-layout: lane owns rows 4lg+ii (strip-local), col 16n+lr ----
  unsigned aw[4][4];
  float qe0r[4], qe1r[4];
  #pragma unroll
  for (int ii = 0; ii < 4; ++ii) {
    int i = r0 + lg * 4 + ii;
    #pragma unroll
    for (int t = 0; t < 4; ++t) aw[ii][t] = adjsh[i][t];
    qe0r[ii] = __shfl(d0, lg * 4 + ii, 64);
    qe1r[ii] = __shfl(d1, lg * 4 + ii, 64);
  }
  float rmax[4] = {-1e30f, -1e30f, -1e30f, -1e30f};
  #pragma unroll
  for (int n = 0; n < 8; ++n) {
    #pragma unroll
    for (int ii = 0; ii < 4; ++ii) {
      unsigned bit = (aw[ii][n >> 1] >> (((n & 1) << 4) + lr)) & 1u;
      float sv = (sacc[n][ii] + (bit ? qe1r[ii] : qe0r[ii])) * 0.125f;
      sacc[n][ii] = sv;
      rmax[ii] = fmaxf(rmax[ii], sv);
    }
  }
  #pragma unroll
  for (int o = 1; o <= 8; o <<= 1) {
    #pragma unroll
    for (int ii = 0; ii < 4; ++ii) rmax[ii] = fmaxf(rmax[ii], __shfl_xor(rmax[ii], o, 64));
  }
  float lsum[4] = {0.f, 0.f, 0.f, 0.f}, a1[4] = {0.f, 0.f, 0.f, 0.f};
  #pragma unroll
  for (int n = 0; n < 8; ++n) {
    #pragma unroll
    for (int ii = 0; ii < 4; ++ii) {
      unsigned bit = (aw[ii][n >> 1] >> (((n & 1) << 4) + lr)) & 1u;
      float pv = __expf(sacc[n][ii] - rmax[ii]);
      lsum[ii] += pv;
      if (bit) a1[ii] += pv;
      uq.P[w][lg * 4 + ii][16 * n + lr] = f2bf(pv);
    }
  }
  #pragma unroll
  for (int o = 1; o <= 8; o <<= 1) {
    #pragma unroll
    for (int ii = 0; ii < 4; ++ii) {
      lsum[ii] += __shfl_xor(lsum[ii], o, 64);
      a1[ii]   += __shfl_xor(a1[ii], o, 64);
    }
  }

  // ---- PV ----
  f32x4 oacc[4];
  #pragma unroll
  for (int n = 0; n < 4; ++n) oacc[n] = (f32x4){0.f, 0.f, 0.f, 0.f};
  #pragma unroll
  for (int kb = 0; kb < 4; ++kb) {
    short8 pa_ = *(const short8*)&uq.P[w][lr][kb * 32 + lg * 8];
    #pragma unroll
    for (int n = 0; n < 4; ++n) {
      short8 vb = *(const short8*)&Vt[16 * n + lr][kb * 32 + lg * 8];
      oacc[n] = __builtin_amdgcn_mfma_f32_16x16x32_bf16(pa_, vb, oacc[n], 0, 0, 0);
    }
  }

  // ---- epilogue ----
  float e0r[4], e1r[4];
  #pragma unroll
  for (int n = 0; n < 4; ++n) { e0r[n] = e0sh[16 * n + lr]; e1r[n] = e1sh[16 * n + lr]; }
  #pragma unroll
  for (int ii = 0; ii < 4; ++ii) {
    float invl = 1.f / lsum[ii];
    float a1n = a1[ii] * invl;
    size_t row = (size_t)(c * SS + r0 + lg * 4 + ii);
    #pragma unroll
    for (int n = 0; n < 4; ++n) {
      float val = oacc[n][ii] * invl + e0r[n] + a1n * (e1r[n] - e0r[n]);
      attn_o[row * INNER + hh * DH + 16 * n + lr] = __float2bfloat16(val);
    }
  }
}

// ---------------- plain MFMA GEMM, gelu->bf16 epilogue (W1) ----------------

__global__ __launch_bounds__(256) void mfma_gemm_gelu(const bf16* __restrict__ A,
    const bf16* __restrict__ Bt, const float* __restrict__ bias, bf16* __restrict__ C1,
    int Nd, int Kd) {
  int bm = blockIdx.x * 64;
  int bn = blockIdx.y * 64;
  int wave = threadIdx.x >> 6;
  int lane = threadIdx.x & 63;
  int wm = (wave & 1) * 32, wn = (wave >> 1) * 32;
  int lr = lane & 15;
  int lk = (lane >> 4) * 8;
  const bf16* pa0 = A + (size_t)(bm + wm + lr) * Kd + lk;
  const bf16* pa1 = pa0 + 16 * (size_t)Kd;
  const bf16* pb0 = Bt + (size_t)(bn + wn + lr) * Kd + lk;
  const bf16* pb1 = pb0 + 16 * (size_t)Kd;
  f32x4 acc00 = {0.f, 0.f, 0.f, 0.f}, acc01 = acc00, acc10 = acc00, acc11 = acc00;
  #pragma unroll 2
  for (int kb = 0; kb < Kd; kb += 32) {
    short8 a0 = *(const short8*)(pa0 + kb);
    short8 a1 = *(const short8*)(pa1 + kb);
    short8 b0 = *(const short8*)(pb0 + kb);
    short8 b1 = *(const short8*)(pb1 + kb);
    acc00 = __builtin_amdgcn_mfma_f32_16x16x32_bf16(a0, b0, acc00, 0, 0, 0);
    acc01 = __builtin_amdgcn_mfma_f32_16x16x32_bf16(a0, b1, acc01, 0, 0, 0);
    acc10 = __builtin_amdgcn_mfma_f32_16x16x32_bf16(a1, b0, acc10, 0, 0, 0);
    acc11 = __builtin_amdgcn_mfma_f32_16x16x32_bf16(a1, b1, acc11, 0, 0, 0);
  }
  int r0 = bm + wm + (lane >> 4) * 4;
  int c0 = bn + wn + lr;
  float bia0 = bias[c0];
  float bia1 = bias[c0 + 16];
  #pragma unroll
  for (int r = 0; r < 2; ++r) {
    #pragma unroll
    for (int c = 0; c < 2; ++c) {
      f32x4 av = (r == 0) ? (c == 0 ? acc00 : acc01) : (c == 0 ? acc10 : acc11);
      float bb = (c == 0) ? bia0 : bia1;
      int col = c0 + c * 16;
      #pragma unroll
      for (int i = 0; i < 4; ++i) {
        float v = av[i] + bb;
        v = 0.5f * v * (1.f + erff(v * 0.70710678118654752f));
        C1[(size_t)(r0 + r * 16 + i) * Nd + col] = __float2bfloat16(v);
      }
    }
  }
}

// ---------------- fused GEMM + scalar-gate epilogue, 16 rows/block (128 blocks) --------
// G1=1: Wo path. rv = x[clusters[row]]; writes nodes1 (f32) and h2 = LN2(nodes1) (bf16).
// G1=0: W2 path. rv = nodes1[row]; writes out[clusters[row]] = x[clusters[row]] + gated.

template <int G1>
__global__ __launch_bounds__(256) void gemm_gate(const bf16* __restrict__ A,
    const bf16* __restrict__ Bt, const float* __restrict__ bias, int Kd,
    const float* __restrict__ gatew, const int* __restrict__ clusters,
    const float* __restrict__ x, const float* __restrict__ nodes1_in,
    float* __restrict__ out_f32, bf16* __restrict__ out_bf,
    const float* __restrict__ lng, const float* __restrict__ lnb) {
  __shared__ float red1[16][4], red2[16][4], gsh[16], msh[16], rsh[16];
  __shared__ int ndsh[16];
  int bm = blockIdx.x * 16;
  int tid = threadIdx.x;
  int w = tid >> 6, l = tid & 63;
  int lg = l >> 4, lr = l & 15;
  if (tid < 16) ndsh[tid] = clusters[bm + tid];

  const bf16* pa = A + (size_t)(bm + lr) * Kd + lg * 8;
  const bf16* pb[4];
  #pragma unroll
  for (int cc = 0; cc < 4; ++cc)
    pb[cc] = Bt + (size_t)(64 * w + 16 * cc + lr) * Kd + lg * 8;

  f32x4 acc[4];
  #pragma unroll
  for (int cc = 0; cc < 4; ++cc) acc[cc] = (f32x4){0.f, 0.f, 0.f, 0.f};
  #pragma unroll 2
  for (int kb = 0; kb < Kd; kb += 32) {
    short8 a0 = *(const short8*)(pa + kb);
    #pragma unroll
    for (int cc = 0; cc < 4; ++cc) {
      short8 bb = *(const short8*)(pb[cc] + kb);
      acc[cc] = __builtin_amdgcn_mfma_f32_16x16x32_bf16(a0, bb, acc[cc], 0, 0, 0);
    }
  }
  __syncthreads();  // ndsh visible

  float av[4][4], rv[4][4];
  #pragma unroll
  for (int cc = 0; cc < 4; ++cc) {
    int col = 64 * w + 16 * cc + lr;
    float bb = bias[col];
    #pragma unroll
    for (int i = 0; i < 4; ++i) {
      int row = 4 * lg + i;
      av[cc][i] = acc[cc][i] + bb;
      if (G1) rv[cc][i] = x[(size_t)ndsh[row] * CC + col];
      else    rv[cc][i] = nodes1_in[(size_t)(bm + row) * CC + col];
    }
  }
  // gate dot partial per row
  #pragma unroll
  for (int i = 0; i < 4; ++i) {
    float s = 0.f;
    #pragma unroll
    for (int cc = 0; cc < 4; ++cc) {
      int col = 64 * w + 16 * cc + lr;
      float a_ = av[cc][i], r_ = rv[cc][i];
      s += a_ * gatew[col] + r_ * gatew[CC + col] + (a_ - r_) * gatew[2 * CC + col];
    }
    #pragma unroll
    for (int o = 1; o <= 8; o <<= 1) s += __shfl_xor(s, o, 64);
    if (lr == 0) red1[4 * lg + i][w] = s;
  }
  __syncthreads();
  if (tid < 16) {
    float t = red1[tid][0] + red1[tid][1] + red1[tid][2] + red1[tid][3];
    gsh[tid] = 1.f / (1.f + __expf(-t));
  }
  __syncthreads();
  float nv[4][4];
  #pragma unroll
  for (int cc = 0; cc < 4; ++cc)
    #pragma unroll
    for (int i = 0; i < 4; ++i) {
      int row = 4 * lg + i;
      nv[cc][i] = fmaf(av[cc][i] - rv[cc][i], gsh[row], rv[cc][i]);
    }
  if (G1) {
    #pragma unroll
    for (int i = 0; i < 4; ++i) {
      float s = 0.f, s2 = 0.f;
      #pragma unroll
      for (int cc = 0; cc < 4; ++cc) { float v = nv[cc][i]; s += v; s2 += v * v; }
      #pragma unroll
      for (int o = 1; o <= 8; o <<= 1) { s += __shfl_xor(s, o, 64); s2 += __shfl_xor(s2, o, 64); }
      if (lr == 0) { red1[4 * lg + i][w] = s; red2[4 * lg + i][w] = s2; }
    }
    __syncthreads();
    if (tid < 16) {
      float s = red1[tid][0] + red1[tid][1] + red1[tid][2] + red1[tid][3];
      float s2 = red2[tid][0] + red2[tid][1] + red2[tid][2] + red2[tid][3];
      float m = s * (1.f / CC);
      float var = s2 * (1.f / CC) - m * m;
      msh[tid] = m;
      rsh[tid] = rsqrtf(var + 1e-5f);
    }
    __syncthreads();
    #pragma unroll
    for (int cc = 0; cc < 4; ++cc) {
      int col = 64 * w + 16 * cc + lr;
      #pragma unroll
      for (int i = 0; i < 4; ++i) {
        int row = 4 * lg + i;
        size_t gr = (size_t)(bm + row);
        float v = nv[cc][i];
        out_f32[gr * CC + col] = v;
        out_bf[gr * CC + col] =
            __float2bfloat16((v - msh[row]) * rsh[row] * lng[col] + lnb[col]);
      }
    }
  } else {
    #pragma unroll
    for (int cc = 0; cc < 4; ++cc) {
      int col = 64 * w + 16 * cc + lr;
      #pragma unroll
      for (int i = 0; i < 4; ++i) {
        int row = 4 * lg + i;
        size_t node = (size_t)ndsh[row];
        out_f32[node * CC + col] = x[node * CC + col] + nv[cc][i];
      }
    }
  }
}

// ---------------- launch ----------------

extern "C" void kernel_launch(void* const* d_in, const int* in_sizes, int n_in,
                              void* d_out, int out_size, void* d_ws, size_t ws_size,
                              hipStream_t stream) {
  const float* x        = (const float*)d_in[0];
  const int*   edge_idx = (const int*)d_in[1];
  const int*   clusters = (const int*)d_in[2];
  const float* adj_emb  = (const float*)d_in[3];
  const float* ln1_g    = (const float*)d_in[4];
  const float* ln1_b    = (const float*)d_in[5];
  const float* Wq       = (const float*)d_in[6];
  const float* bq       = (const float*)d_in[7];
  const float* Wkv      = (const float*)d_in[8];
  const float* bkv      = (const float*)d_in[9];
  const float* We       = (const float*)d_in[10];
  const float* be       = (const float*)d_in[11];
  const float* Wo       = (const float*)d_in[12];
  const float* bo       = (const float*)d_in[13];
  const float* gate1_w  = (const float*)d_in[14];
  const float* ln2_g    = (const float*)d_in[15];
  const float* ln2_b    = (const float*)d_in[16];
  const float* W1       = (const float*)d_in[17];
  const float* b1       = (const float*)d_in[18];
  const float* W2       = (const float*)d_in[19];
  const float* b2       = (const float*)d_in[20];
  const float* gate2_w  = (const float*)d_in[21];
  float* out = (float*)d_out;

  char* ws = (char*)d_ws;
  int*      node2c = (int*)(ws + 0);            // 8KB
  int*      node2p = (int*)(ws + 8192);         // 8KB
  unsigned* adjb   = (unsigned*)(ws + 16384);   // 32KB [ws+16384, ws+49152)
  float*    e01    = (float*)(ws + 49152);      // 4KB
  float2*   rope   = (float2*)(ws + 53248);     // 32KB [128][32]
  float*    bqkv   = (float*)(ws + 86016);      // 6KB
  const size_t MB = 1ull << 20;
  char* w2 = ws + 131072;
  bf16*  h      = (bf16*) (w2 + 0 * MB);    // 1MB  [2048][256]
  bf16*  attn_o = (bf16*) (w2 + 1 * MB);    // 2MB  [2048][512]
  float* nodes1 = (float*)(w2 + 3 * MB);    // 2MB
  bf16*  h2     = (bf16*) (w2 + 5 * MB);    // 1MB
  bf16*  ff1    = (bf16*) (w2 + 6 * MB);    // 4MB  [2048][1024]
  bf16*  Wqkvt  = (bf16*) (w2 + 10 * MB);              // 768KB [1536][256]
  bf16*  Wot    = (bf16*) (w2 + 10 * MB + 768 * 1024); // 256KB [256][512]
  bf16*  W1t    = (bf16*) (w2 + 11 * MB);              // 512KB [1024][256]
  bf16*  W2t    = (bf16*) (w2 + 11 * MB + 512 * 1024); // 512KB [256][1024]
  if (ws_size < 131072 + 12 * MB) return;

  int E = in_sizes[1] / 2;

  prep_ln<<<2368, 256, 0, stream>>>(clusters, adj_emb, We, be, Wq, Wkv, Wo, W1, W2, bq, bkv,
                                    x, ln1_g, ln1_b,
                                    node2c, node2p, adjb, e01, rope, bqkv,
                                    Wqkvt, Wot, W1t, W2t, h);
  build_adj<<<(E + 255) / 256, 256, 0, stream>>>(edge_idx, node2c, node2p, adjb, E);
  qkv_attn<<<128, 512, 0, stream>>>(h, Wqkvt, bqkv, adjb, e01, rope, attn_o);
  gemm_gate<1><<<128, 256, 0, stream>>>(attn_o, Wot, bo, INNER, gate1_w, clusters,
                                        x, nullptr, nodes1, h2, ln2_g, ln2_b);
  mfma_gemm_gelu<<<dim3(32, 16), 256, 0, stream>>>(h2, W1t, b1, ff1, 4 * CC, CC);
  gemm_gate<0><<<128, 256, 0, stream>>>(ff1, W2t, b2, 4 * CC, gate2_w, clusters,
                                        x, nodes1, out, nullptr, nullptr, nullptr);
}

// Round 9
// 83.726 us; speedup vs baseline: 1.2079x; 1.2079x over previous
//
#include <hip/hip_runtime.h>
#include <hip/hip_bf16.h>
#include <math.h>

#define NN 2048
#define CC 256
#define KK 16
#define SS 128
#define HH 8
#define DH 64
#define INNER 512

using short8 = __attribute__((ext_vector_type(8))) short;
using f32x4  = __attribute__((ext_vector_type(4))) float;
typedef __hip_bfloat16 bf16;

__device__ __forceinline__ short f2bf(float f) {
  bf16 b = __float2bfloat16(f);
  short s; __builtin_memcpy(&s, &b, 2); return s;
}
__device__ __forceinline__ float bf2f(short s) {
  unsigned u = ((unsigned)(unsigned short)s) << 16;
  float f; __builtin_memcpy(&f, &u, 4); return f;
}

// ---------------- helpers ----------------

__device__ __forceinline__ void block_reduce1(float v1, float* red, float& o1) {
  #pragma unroll
  for (int o = 32; o > 0; o >>= 1) v1 += __shfl_xor(v1, o, 64);
  __syncthreads();
  int wid = threadIdx.x >> 6;
  if ((threadIdx.x & 63) == 0) red[wid] = v1;
  __syncthreads();
  o1 = red[0] + red[1] + red[2] + red[3];
}

__device__ __forceinline__ void block_reduce2(float v1, float v2, float* red, float& o1, float& o2) {
  #pragma unroll
  for (int o = 32; o > 0; o >>= 1) { v1 += __shfl_xor(v1, o, 64); v2 += __shfl_xor(v2, o, 64); }
  __syncthreads();
  int wid = threadIdx.x >> 6;
  if ((threadIdx.x & 63) == 0) { red[wid] = v1; red[4 + wid] = v2; }
  __syncthreads();
  o1 = red[0] + red[1] + red[2] + red[3];
  o2 = red[4] + red[5] + red[6] + red[7];
}

// ---------------- prep + LN1 ----------------
// BLOCK MAP (grid 2368):
//   [0,8)      node->cluster/pos maps
//   [8,40)     zero adjb: 32 blocks x 256 = 8192 words = 32KB (EXACTLY adjb's size)
//   [40,42)    e01
//   [42,58)    rope table [128][32] float2
//   [58,64)    bqkv concat [1536]
//   [64,320)   weight transposes, 256 blocks of 64x64 f32 tiles via LDS:
//              [64,96) Wq  [96,160) Wkv  [160,192) Wo  [192,256) W1  [256,320) W2
//   [320,2368) LN1: row = b - 320

#define LNB 320

__global__ __launch_bounds__(256) void prep_ln(const int* __restrict__ clusters,
    const float* __restrict__ adj_emb, const float* __restrict__ We, const float* __restrict__ be,
    const float* __restrict__ Wq, const float* __restrict__ Wkv, const float* __restrict__ Wo,
    const float* __restrict__ W1, const float* __restrict__ W2,
    const float* __restrict__ bq, const float* __restrict__ bkv,
    const float* __restrict__ x, const float* __restrict__ ln1_g, const float* __restrict__ ln1_b,
    int* __restrict__ node2c, int* __restrict__ node2p, unsigned* __restrict__ adjb,
    float* __restrict__ e01, float2* __restrict__ rope, float* __restrict__ bqkv,
    bf16* __restrict__ Wqkvt, bf16* __restrict__ Wot, bf16* __restrict__ W1t,
    bf16* __restrict__ W2t, bf16* __restrict__ h) {
  __shared__ float red[8];
  __shared__ float tile[64][65];
  int b = blockIdx.x, tid = threadIdx.x;
  if (b >= LNB) {                                // LN1 (gathered)
    int row = b - LNB;
    int node = clusters[row];
    float v = x[(size_t)node * CC + tid];
    float s, s2;
    block_reduce2(v, v * v, red, s, s2);
    float m = s * (1.f / CC);
    float var = s2 * (1.f / CC) - m * m;
    float r = rsqrtf(var + 1e-5f);
    h[(size_t)row * CC + tid] = __float2bfloat16((v - m) * r * ln1_g[tid] + ln1_b[tid]);
    return;
  }
  if (b >= 64) {                                 // weight transpose tiles
    int t = b - 64;
    const float* src; bf16* dst; int srcN, dstK, k0, n0;
    if (t < 32)       { src = Wq;  dst = Wqkvt;             srcN = 512;  dstK = 256;
                        k0 = (t & 3) * 64;        n0 = (t >> 2) * 64; }
    else if (t < 96)  { int u = t - 32;  src = Wkv; dst = Wqkvt + 512 * 256; srcN = 1024; dstK = 256;
                        k0 = (u & 3) * 64;        n0 = (u >> 2) * 64; }
    else if (t < 128) { int u = t - 96;  src = Wo;  dst = Wot; srcN = 256;  dstK = 512;
                        k0 = (u & 7) * 64;        n0 = (u >> 3) * 64; }
    else if (t < 192) { int u = t - 128; src = W1;  dst = W1t; srcN = 1024; dstK = 256;
                        k0 = (u & 3) * 64;        n0 = (u >> 2) * 64; }
    else              { int u = t - 192; src = W2;  dst = W2t; srcN = 256;  dstK = 1024;
                        k0 = (u & 15) * 64;       n0 = (u >> 4) * 64; }
    int rl = tid >> 6, cl = tid & 63;
    #pragma unroll
    for (int it = 0; it < 16; ++it) {
      int r = it * 4 + rl;
      tile[r][cl] = src[(size_t)(k0 + r) * srcN + n0 + cl];
    }
    __syncthreads();
    #pragma unroll
    for (int it = 0; it < 16; ++it) {
      int n = it * 4 + rl;
      dst[(size_t)(n0 + n) * dstK + k0 + cl] = __float2bfloat16(tile[cl][n]);
    }
    return;
  }
  if (b < 8) {                                   // node->cluster/pos maps
    int r = b * 256 + tid;
    int node = clusters[r];
    node2c[node] = r >> 7;
    node2p[node] = r & 127;
  } else if (b < 40) {                           // zero adjacency bitmask: 8192 words total
    adjb[(b - 8) * 256 + tid] = 0u;
  } else if (b < 42) {                           // e0/e1 = adj_emb @ We + be
    int j = (b - 40) * 256 + tid;
    float a0 = 0.f, a1 = 0.f;
    for (int c = 0; c < CC; ++c) {
      float w = We[(size_t)c * INNER + j];
      a0 = fmaf(adj_emb[c], w, a0);
      a1 = fmaf(adj_emb[CC + c], w, a1);
    }
    e01[j] = a0 + be[j];
    e01[INNER + j] = a1 + be[j];
  } else if (b < 58) {                           // rope table [128][32] (cos, sin)
    int idx = (b - 42) * 256 + tid;
    int s = idx >> 5, t = idx & 31;
    float ang = (float)s * exp2f(-(float)t * 0.41524101186092029f);  // s * 10000^(-t/32)
    float sn, cs;
    sincosf(ang, &sn, &cs);
    rope[idx] = make_float2(cs, sn);
  } else {                                       // bias concat [1536]
    int idx = (b - 58) * 256 + tid;
    bqkv[idx] = idx < 512 ? bq[idx] : bkv[idx - 512];
  }
}

__global__ void build_adj(const int* __restrict__ ei, const int* __restrict__ node2c,
                          const int* __restrict__ node2p, unsigned* __restrict__ adj, int E) {
  int t = blockIdx.x * 256 + threadIdx.x;
  if (t >= E) return;
  int u = ei[t], v = ei[E + t];
  int cu = node2c[u];
  if (cu == node2c[v]) {
    int pu = node2p[u], pv = node2p[v];
    atomicOr(&adj[(cu * 128 + pu) * 4 + (pv >> 5)], 1u << (pv & 31));
  }
}

// ---------------- MFMA GEMM ----------------
// MODE 0: f32 out C1. MODE 1: gelu -> bf16 C1.
// MODE 3: fused QKV (Nd=1536): cols [0,512) rotary->qb(C1), [512,1024) rotary->kbg(C2),
//         [1024,1536) ->vbg(C3). Rotation pairs via shfl_xor(1); rope table [128][32].

template <int MODE>
__global__ __launch_bounds__(256) void mfma_gemm(const bf16* __restrict__ A,
    const bf16* __restrict__ Bt, const float* __restrict__ bias,
    void* __restrict__ C1, void* __restrict__ C2, void* __restrict__ C3,
    const float2* __restrict__ rope, int Nd, int Kd) {
  int bm = blockIdx.x * 64;
  int bn = blockIdx.y * 64;
  int wave = threadIdx.x >> 6;
  int lane = threadIdx.x & 63;
  int wm = (wave & 1) * 32, wn = (wave >> 1) * 32;
  int lr = lane & 15;
  int lk = (lane >> 4) * 8;
  const bf16* pa0 = A + (size_t)(bm + wm + lr) * Kd + lk;
  const bf16* pa1 = pa0 + 16 * (size_t)Kd;
  const bf16* pb0 = Bt + (size_t)(bn + wn + lr) * Kd + lk;
  const bf16* pb1 = pb0 + 16 * (size_t)Kd;
  f32x4 acc00 = {0.f, 0.f, 0.f, 0.f}, acc01 = acc00, acc10 = acc00, acc11 = acc00;
  #pragma unroll 2
  for (int kb = 0; kb < Kd; kb += 32) {
    short8 a0 = *(const short8*)(pa0 + kb);
    short8 a1 = *(const short8*)(pa1 + kb);
    short8 b0 = *(const short8*)(pb0 + kb);
    short8 b1 = *(const short8*)(pb1 + kb);
    acc00 = __builtin_amdgcn_mfma_f32_16x16x32_bf16(a0, b0, acc00, 0, 0, 0);
    acc01 = __builtin_amdgcn_mfma_f32_16x16x32_bf16(a0, b1, acc01, 0, 0, 0);
    acc10 = __builtin_amdgcn_mfma_f32_16x16x32_bf16(a1, b0, acc10, 0, 0, 0);
    acc11 = __builtin_amdgcn_mfma_f32_16x16x32_bf16(a1, b1, acc11, 0, 0, 0);
  }
  int r0 = bm + wm + (lane >> 4) * 4;
  int c0 = bn + wn + lr;
  float bia0 = bias[c0];
  float bia1 = bias[c0 + 16];
  float vals[2][2][4];
  #pragma unroll
  for (int r = 0; r < 2; ++r) {
    #pragma unroll
    for (int c = 0; c < 2; ++c) {
      f32x4 av = (r == 0) ? (c == 0 ? acc00 : acc01) : (c == 0 ? acc10 : acc11);
      float bb = (c == 0) ? bia0 : bia1;
      #pragma unroll
      for (int i = 0; i < 4; ++i) vals[r][c][i] = av[i] + bb;
    }
  }
  if (MODE == 3) {
    int seg = c0 >> 9;  // block-uniform: 0=q, 1=k, 2=v
    if (seg == 2) {
      #pragma unroll
      for (int r = 0; r < 2; ++r)
        #pragma unroll
        for (int c = 0; c < 2; ++c)
          #pragma unroll
          for (int i = 0; i < 4; ++i)
            ((bf16*)C3)[(size_t)(r0 + r * 16 + i) * 512 + (c0 - 1024 + 16 * c)] =
                __float2bfloat16(vals[r][c][i]);
    } else {
      bf16* dst = seg ? (bf16*)C2 : (bf16*)C1;
      int colbase = c0 - seg * 512;
      #pragma unroll
      for (int r = 0; r < 2; ++r) {
        #pragma unroll
        for (int c = 0; c < 2; ++c) {
          int col = colbase + 16 * c;
          int tp = (col & 63) >> 1;
          bool odd = (col & 1) != 0;
          #pragma unroll
          for (int i = 0; i < 4; ++i) {
            int row = r0 + r * 16 + i;
            float v = vals[r][c][i];
            float p = __shfl_xor(v, 1, 64);          // partner col (col^1)
            float2 cssn = rope[(row & 127) * 32 + tp];
            float o = odd ? fmaf(v, cssn.x, p * cssn.y) : fmaf(v, cssn.x, -p * cssn.y);
            dst[(size_t)row * 512 + col] = __float2bfloat16(o);
          }
        }
      }
    }
  } else {
    #pragma unroll
    for (int r = 0; r < 2; ++r) {
      #pragma unroll
      for (int c = 0; c < 2; ++c) {
        int col = c0 + c * 16;
        #pragma unroll
        for (int i = 0; i < 4; ++i) {
          float v = vals[r][c][i];
          size_t row = (size_t)(r0 + r * 16 + i);
          if (MODE == 1) {
            v = 0.5f * v * (1.f + erff(v * 0.70710678118654752f));
            ((bf16*)C1)[row * Nd + col] = __float2bfloat16(v);
          } else {
            ((float*)C1)[row * Nd + col] = v;
          }
        }
      }
    }
  }
}

// ---------------- MFMA attention: block = (cluster, head, q-half), 4 waves x 16 rows ------

__global__ __launch_bounds__(256) void attn_mfma(const bf16* __restrict__ qb,
    const bf16* __restrict__ kbg, const bf16* __restrict__ vbg,
    const unsigned* __restrict__ adjb, const float* __restrict__ e01,
    bf16* __restrict__ attn_o) {
  __shared__ short Kb[SS][72];
  __shared__ short Vt[DH][136];
  __shared__ short Psh[4][16][136];
  __shared__ unsigned adjsh[SS][4];
  __shared__ float e0sh[DH], e1sh[DH];

  int blk = blockIdx.x;
  int half = blk & 1, h = (blk >> 1) & 7, c = blk >> 4;
  int tid = threadIdx.x;
  int w = tid >> 6, l = tid & 63;
  int lg = l >> 4, lr = l & 15;

  // ---- staging ----
  {
    int j = tid & 127, hd = tid >> 7;
    const short8* ksrc = (const short8*)(kbg + ((size_t)(c * SS + j)) * INNER + h * DH + hd * 32);
    const short8* vsrc = (const short8*)(vbg + ((size_t)(c * SS + j)) * INNER + h * DH + hd * 32);
    #pragma unroll
    for (int ch = 0; ch < 4; ++ch) {
      *(short8*)&Kb[j][hd * 32 + ch * 8] = ksrc[ch];
      short8 vv = vsrc[ch];
      #pragma unroll
      for (int e = 0; e < 8; ++e) Vt[hd * 32 + ch * 8 + e][j] = vv[e];
    }
  }
  if (tid < 128) {
    *(uint4*)&adjsh[tid][0] = *(const uint4*)(adjb + (size_t)(c * SS + tid) * 4);
  } else if (tid < 192) {
    e0sh[tid - 128] = e01[h * DH + (tid - 128)];
  } else {
    e1sh[tid - 192] = e01[INNER + h * DH + (tid - 192)];
  }
  __syncthreads();

  int ib = half * 64 + w * 16;

  // ---- Q frags + qe dots (rows ib+lr) ----
  const bf16* qrow = qb + ((size_t)(c * SS + ib + lr)) * INNER + h * DH + lg * 8;
  short8 aq0 = *(const short8*)(qrow);
  short8 aq1 = *(const short8*)(qrow + 32);
  float d0 = 0.f, d1 = 0.f;
  #pragma unroll
  for (int e = 0; e < 8; ++e) {
    float q0 = bf2f(aq0[e]), q1 = bf2f(aq1[e]);
    d0 += q0 * e0sh[lg * 8 + e] + q1 * e0sh[lg * 8 + 32 + e];
    d1 += q0 * e1sh[lg * 8 + e] + q1 * e1sh[lg * 8 + 32 + e];
  }
  d0 += __shfl_xor(d0, 16, 64); d0 += __shfl_xor(d0, 32, 64);
  d1 += __shfl_xor(d1, 16, 64); d1 += __shfl_xor(d1, 32, 64);

  // ---- QK^T ----
  f32x4 sacc[8];
  #pragma unroll
  for (int n = 0; n < 8; ++n) sacc[n] = (f32x4){0.f, 0.f, 0.f, 0.f};
  #pragma unroll
  for (int n = 0; n < 8; ++n) {
    short8 bk0 = *(const short8*)&Kb[16 * n + lr][lg * 8];
    short8 bk1 = *(const short8*)&Kb[16 * n + lr][lg * 8 + 32];
    sacc[n] = __builtin_amdgcn_mfma_f32_16x16x32_bf16(aq0, bk0, sacc[n], 0, 0, 0);
    sacc[n] = __builtin_amdgcn_mfma_f32_16x16x32_bf16(aq1, bk1, sacc[n], 0, 0, 0);
  }

  // ---- softmax on C-layout ----
  unsigned aw[4][4];
  float qe0r[4], qe1r[4];
  #pragma unroll
  for (int ii = 0; ii < 4; ++ii) {
    int i = ib + lg * 4 + ii;
    #pragma unroll
    for (int t = 0; t < 4; ++t) aw[ii][t] = adjsh[i][t];
    qe0r[ii] = __shfl(d0, lg * 4 + ii, 64);
    qe1r[ii] = __shfl(d1, lg * 4 + ii, 64);
  }
  float rmax[4] = {-1e30f, -1e30f, -1e30f, -1e30f};
  #pragma unroll
  for (int n = 0; n < 8; ++n) {
    #pragma unroll
    for (int ii = 0; ii < 4; ++ii) {
      unsigned bit = (aw[ii][n >> 1] >> (((n & 1) << 4) + lr)) & 1u;
      float sv = (sacc[n][ii] + (bit ? qe1r[ii] : qe0r[ii])) * 0.125f;
      sacc[n][ii] = sv;
      rmax[ii] = fmaxf(rmax[ii], sv);
    }
  }
  #pragma unroll
  for (int o = 1; o <= 8; o <<= 1) {
    #pragma unroll
    for (int ii = 0; ii < 4; ++ii) rmax[ii] = fmaxf(rmax[ii], __shfl_xor(rmax[ii], o, 64));
  }
  float lsum[4] = {0.f, 0.f, 0.f, 0.f}, a1[4] = {0.f, 0.f, 0.f, 0.f};
  #pragma unroll
  for (int n = 0; n < 8; ++n) {
    #pragma unroll
    for (int ii = 0; ii < 4; ++ii) {
      unsigned bit = (aw[ii][n >> 1] >> (((n & 1) << 4) + lr)) & 1u;
      float pv = __expf(sacc[n][ii] - rmax[ii]);
      lsum[ii] += pv;
      if (bit) a1[ii] += pv;
      Psh[w][lg * 4 + ii][16 * n + lr] = f2bf(pv);
    }
  }
  #pragma unroll
  for (int o = 1; o <= 8; o <<= 1) {
    #pragma unroll
    for (int ii = 0; ii < 4; ++ii) {
      lsum[ii] += __shfl_xor(lsum[ii], o, 64);
      a1[ii]   += __shfl_xor(a1[ii], o, 64);
    }
  }

  // ---- PV ----
  f32x4 oacc[4];
  #pragma unroll
  for (int n = 0; n < 4; ++n) oacc[n] = (f32x4){0.f, 0.f, 0.f, 0.f};
  #pragma unroll
  for (int kb = 0; kb < 4; ++kb) {
    short8 pa = *(const short8*)&Psh[w][lr][kb * 32 + lg * 8];
    #pragma unroll
    for (int n = 0; n < 4; ++n) {
      short8 vb = *(const short8*)&Vt[16 * n + lr][kb * 32 + lg * 8];
      oacc[n] = __builtin_amdgcn_mfma_f32_16x16x32_bf16(pa, vb, oacc[n], 0, 0, 0);
    }
  }

  // ---- epilogue ----
  float e0r[4], e1r[4];
  #pragma unroll
  for (int n = 0; n < 4; ++n) { e0r[n] = e0sh[16 * n + lr]; e1r[n] = e1sh[16 * n + lr]; }
  #pragma unroll
  for (int ii = 0; ii < 4; ++ii) {
    float invl = 1.f / lsum[ii];
    float a1n = a1[ii] * invl;
    size_t row = (size_t)(c * SS + ib + lg * 4 + ii);
    #pragma unroll
    for (int n = 0; n < 4; ++n) {
      float val = oacc[n][ii] * invl + e0r[n] + a1n * (e1r[n] - e0r[n]);
      attn_o[row * INNER + h * DH + 16 * n + lr] = __float2bfloat16(val);
    }
  }
}

// ---------------- gate1 + LN2 fused ----------------

__global__ __launch_bounds__(256) void gate1_ln2(const float* __restrict__ a,
    const float* __restrict__ x, const int* __restrict__ cl, const float* __restrict__ w,
    const float* __restrict__ g, const float* __restrict__ b,
    float* __restrict__ nodes1, bf16* __restrict__ h2) {
  __shared__ float red[8];
  int row = blockIdx.x;
  int c = threadIdx.x;
  float av = a[(size_t)row * CC + c];
  float rv = x[(size_t)cl[row] * CC + c];
  float contrib = av * w[c] + rv * w[CC + c] + (av - rv) * w[2 * CC + c];
  float t;
  block_reduce1(contrib, red, t);
  float gate = 1.f / (1.f + __expf(-t));
  float n1 = av * gate + rv * (1.f - gate);
  nodes1[(size_t)row * CC + c] = n1;
  float s, s2;
  block_reduce2(n1, n1 * n1, red, s, s2);
  float m = s * (1.f / CC);
  float var = s2 * (1.f / CC) - m * m;
  float r = rsqrtf(var + 1e-5f);
  h2[(size_t)row * CC + c] = __float2bfloat16((n1 - m) * r * g[c] + b[c]);
}

// ---------------- gate2 + final add fused ----------------

__global__ __launch_bounds__(256) void gate2_add(const float* __restrict__ a,
    const float* __restrict__ nodes1, const int* __restrict__ clusters,
    const float* __restrict__ w, const float* __restrict__ x, float* __restrict__ outp) {
  __shared__ float red[8];
  int row = blockIdx.x;
  int c = threadIdx.x;
  float av = a[(size_t)row * CC + c];
  float rv = nodes1[(size_t)row * CC + c];
  float contrib = av * w[c] + rv * w[CC + c] + (av - rv) * w[2 * CC + c];
  float t;
  block_reduce1(contrib, red, t);
  float gate = 1.f / (1.f + __expf(-t));
  float n2 = av * gate + rv * (1.f - gate);
  int node = clusters[row];
  outp[(size_t)node * CC + c] = x[(size_t)node * CC + c] + n2;
}

// ---------------- launch ----------------

extern "C" void kernel_launch(void* const* d_in, const int* in_sizes, int n_in,
                              void* d_out, int out_size, void* d_ws, size_t ws_size,
                              hipStream_t stream) {
  const float* x        = (const float*)d_in[0];
  const int*   edge_idx = (const int*)d_in[1];
  const int*   clusters = (const int*)d_in[2];
  const float* adj_emb  = (const float*)d_in[3];
  const float* ln1_g    = (const float*)d_in[4];
  const float* ln1_b    = (const float*)d_in[5];
  const float* Wq       = (const float*)d_in[6];
  const float* bq       = (const float*)d_in[7];
  const float* Wkv      = (const float*)d_in[8];
  const float* bkv      = (const float*)d_in[9];
  const float* We       = (const float*)d_in[10];
  const float* be       = (const float*)d_in[11];
  const float* Wo       = (const float*)d_in[12];
  const float* bo       = (const float*)d_in[13];
  const float* gate1_w  = (const float*)d_in[14];
  const float* ln2_g    = (const float*)d_in[15];
  const float* ln2_b    = (const float*)d_in[16];
  const float* W1       = (const float*)d_in[17];
  const float* b1       = (const float*)d_in[18];
  const float* W2       = (const float*)d_in[19];
  const float* b2       = (const float*)d_in[20];
  const float* gate2_w  = (const float*)d_in[21];
  float* out = (float*)d_out;

  char* ws = (char*)d_ws;
  int*      node2c = (int*)(ws + 0);            // 8KB
  int*      node2p = (int*)(ws + 8192);         // 8KB
  unsigned* adjb   = (unsigned*)(ws + 16384);   // 32KB [ws+16384, ws+49152)
  float*    e01    = (float*)(ws + 49152);      // 4KB
  float2*   rope   = (float2*)(ws + 53248);     // 32KB [128][32]
  float*    bqkv   = (float*)(ws + 86016);      // 6KB
  const size_t MB = 1ull << 20;
  char* w2 = ws + 131072;
  bf16*  h      = (bf16*) (w2 + 0 * MB);    // 1MB  [2048][256]
  bf16*  qb     = (bf16*) (w2 + 1 * MB);    // 2MB  [2048][512]
  bf16*  kbg    = (bf16*) (w2 + 3 * MB);    // 2MB
  bf16*  vbg    = (bf16*) (w2 + 5 * MB);    // 2MB
  bf16*  attn_o = (bf16*) (w2 + 7 * MB);    // 2MB
  float* proj   = (float*)(w2 + 9 * MB);    // 2MB
  float* nodes1 = (float*)(w2 + 11 * MB);   // 2MB
  bf16*  h2     = (bf16*) (w2 + 13 * MB);   // 1MB
  bf16*  ff1    = (bf16*) (w2 + 14 * MB);   // 4MB  [2048][1024]
  float* ff2    = (float*)(w2 + 18 * MB);   // 2MB
  bf16*  Wqkvt  = (bf16*) (w2 + 20 * MB);              // 768KB [1536][256]
  bf16*  Wot    = (bf16*) (w2 + 20 * MB + 768 * 1024); // 256KB [256][512]
  bf16*  W1t    = (bf16*) (w2 + 21 * MB);              // 512KB [1024][256]
  bf16*  W2t    = (bf16*) (w2 + 21 * MB + 512 * 1024); // 512KB [256][1024]
  if (ws_size < 131072 + 22 * MB) return;

  int E = in_sizes[1] / 2;

  prep_ln<<<2368, 256, 0, stream>>>(clusters, adj_emb, We, be, Wq, Wkv, Wo, W1, W2, bq, bkv,
                                    x, ln1_g, ln1_b,
                                    node2c, node2p, adjb, e01, rope, bqkv,
                                    Wqkvt, Wot, W1t, W2t, h);
  build_adj<<<(E + 255) / 256, 256, 0, stream>>>(edge_idx, node2c, node2p, adjb, E);
  mfma_gemm<3><<<dim3(32, 24), 256, 0, stream>>>(h, Wqkvt, bqkv, qb, kbg, vbg, rope, 1536, CC);
  attn_mfma<<<256, 256, 0, stream>>>(qb, kbg, vbg, adjb, e01, attn_o);
  mfma_gemm<0><<<dim3(32, 4), 256, 0, stream>>>(attn_o, Wot, bo, proj, nullptr, nullptr,
                                                nullptr, CC, INNER);
  gate1_ln2<<<NN, 256, 0, stream>>>(proj, x, clusters, gate1_w, ln2_g, ln2_b, nodes1, h2);
  mfma_gemm<1><<<dim3(32, 16), 256, 0, stream>>>(h2, W1t, b1, ff1, nullptr, nullptr,
                                                 nullptr, 4 * CC, CC);
  mfma_gemm<0><<<dim3(32, 4), 256, 0, stream>>>(ff1, W2t, b2, ff2, nullptr, nullptr,
                                                nullptr, CC, 4 * CC);
  gate2_add<<<NN, 256, 0, stream>>>(ff2, nodes1, clusters, gate2_w, x, out);
}

// Round 10
// 77.420 us; speedup vs baseline: 1.3062x; 1.0815x over previous
//
#include <hip/hip_runtime.h>
#include <hip/hip_bf16.h>
#include <math.h>

#define NN 2048
#define CC 256
#define KK 16
#define SS 128
#define HH 8
#define DH 64
#define INNER 512

using short8 = __attribute__((ext_vector_type(8))) short;
using f32x4  = __attribute__((ext_vector_type(4))) float;
typedef __hip_bfloat16 bf16;

__device__ __forceinline__ short f2bf(float f) {
  bf16 b = __float2bfloat16(f);
  short s; __builtin_memcpy(&s, &b, 2); return s;
}
__device__ __forceinline__ float bf2f(short s) {
  unsigned u = ((unsigned)(unsigned short)s) << 16;
  float f; __builtin_memcpy(&f, &u, 4); return f;
}

// ---------------- helpers ----------------

__device__ __forceinline__ void block_reduce1(float v1, float* red, float& o1) {
  #pragma unroll
  for (int o = 32; o > 0; o >>= 1) v1 += __shfl_xor(v1, o, 64);
  __syncthreads();
  int wid = threadIdx.x >> 6;
  if ((threadIdx.x & 63) == 0) red[wid] = v1;
  __syncthreads();
  o1 = red[0] + red[1] + red[2] + red[3];
}

__device__ __forceinline__ void block_reduce2(float v1, float v2, float* red, float& o1, float& o2) {
  #pragma unroll
  for (int o = 32; o > 0; o >>= 1) { v1 += __shfl_xor(v1, o, 64); v2 += __shfl_xor(v2, o, 64); }
  __syncthreads();
  int wid = threadIdx.x >> 6;
  if ((threadIdx.x & 63) == 0) { red[wid] = v1; red[4 + wid] = v2; }
  __syncthreads();
  o1 = red[0] + red[1] + red[2] + red[3];
  o2 = red[4] + red[5] + red[6] + red[7];
}

// ---------------- prep + LN1 ----------------
// BLOCK MAP (grid 2368):
//   [0,8)      node->cluster/pos maps
//   [8,40)     zero adjb: 32 blocks x 256 = 8192 words = 32KB (EXACTLY adjb's size)
//   [40,42)    e01
//   [42,58)    rope table [128][32] float2
//   [58,64)    bqkv concat [1536]
//   [64,320)   weight transposes, 256 blocks of 64x64 f32 tiles via LDS
//   [320,2368) LN1: row = b - 320

#define LNB 320

__global__ __launch_bounds__(256) void prep_ln(const int* __restrict__ clusters,
    const float* __restrict__ adj_emb, const float* __restrict__ We, const float* __restrict__ be,
    const float* __restrict__ Wq, const float* __restrict__ Wkv, const float* __restrict__ Wo,
    const float* __restrict__ W1, const float* __restrict__ W2,
    const float* __restrict__ bq, const float* __restrict__ bkv,
    const float* __restrict__ x, const float* __restrict__ ln1_g, const float* __restrict__ ln1_b,
    int* __restrict__ node2c, int* __restrict__ node2p, unsigned* __restrict__ adjb,
    float* __restrict__ e01, float2* __restrict__ rope, float* __restrict__ bqkv,
    bf16* __restrict__ Wqkvt, bf16* __restrict__ Wot, bf16* __restrict__ W1t,
    bf16* __restrict__ W2t, bf16* __restrict__ h) {
  __shared__ float red[8];
  __shared__ float tile[64][65];
  int b = blockIdx.x, tid = threadIdx.x;
  if (b >= LNB) {                                // LN1 (gathered)
    int row = b - LNB;
    int node = clusters[row];
    float v = x[(size_t)node * CC + tid];
    float s, s2;
    block_reduce2(v, v * v, red, s, s2);
    float m = s * (1.f / CC);
    float var = s2 * (1.f / CC) - m * m;
    float r = rsqrtf(var + 1e-5f);
    h[(size_t)row * CC + tid] = __float2bfloat16((v - m) * r * ln1_g[tid] + ln1_b[tid]);
    return;
  }
  if (b >= 64) {                                 // weight transpose tiles
    int t = b - 64;
    const float* src; bf16* dst; int srcN, dstK, k0, n0;
    if (t < 32)       { src = Wq;  dst = Wqkvt;             srcN = 512;  dstK = 256;
                        k0 = (t & 3) * 64;        n0 = (t >> 2) * 64; }
    else if (t < 96)  { int u = t - 32;  src = Wkv; dst = Wqkvt + 512 * 256; srcN = 1024; dstK = 256;
                        k0 = (u & 3) * 64;        n0 = (u >> 2) * 64; }
    else if (t < 128) { int u = t - 96;  src = Wo;  dst = Wot; srcN = 256;  dstK = 512;
                        k0 = (u & 7) * 64;        n0 = (u >> 3) * 64; }
    else if (t < 192) { int u = t - 128; src = W1;  dst = W1t; srcN = 1024; dstK = 256;
                        k0 = (u & 3) * 64;        n0 = (u >> 2) * 64; }
    else              { int u = t - 192; src = W2;  dst = W2t; srcN = 256;  dstK = 1024;
                        k0 = (u & 15) * 64;       n0 = (u >> 4) * 64; }
    int rl = tid >> 6, cl = tid & 63;
    #pragma unroll
    for (int it = 0; it < 16; ++it) {
      int r = it * 4 + rl;
      tile[r][cl] = src[(size_t)(k0 + r) * srcN + n0 + cl];
    }
    __syncthreads();
    #pragma unroll
    for (int it = 0; it < 16; ++it) {
      int n = it * 4 + rl;
      dst[(size_t)(n0 + n) * dstK + k0 + cl] = __float2bfloat16(tile[cl][n]);
    }
    return;
  }
  if (b < 8) {                                   // node->cluster/pos maps
    int r = b * 256 + tid;
    int node = clusters[r];
    node2c[node] = r >> 7;
    node2p[node] = r & 127;
  } else if (b < 40) {                           // zero adjacency bitmask: 8192 words total
    adjb[(b - 8) * 256 + tid] = 0u;
  } else if (b < 42) {                           // e0/e1 = adj_emb @ We + be
    int j = (b - 40) * 256 + tid;
    float a0 = 0.f, a1 = 0.f;
    for (int c = 0; c < CC; ++c) {
      float w = We[(size_t)c * INNER + j];
      a0 = fmaf(adj_emb[c], w, a0);
      a1 = fmaf(adj_emb[CC + c], w, a1);
    }
    e01[j] = a0 + be[j];
    e01[INNER + j] = a1 + be[j];
  } else if (b < 58) {                           // rope table [128][32] (cos, sin)
    int idx = (b - 42) * 256 + tid;
    int s = idx >> 5, t = idx & 31;
    float ang = (float)s * exp2f(-(float)t * 0.41524101186092029f);  // s * 10000^(-t/32)
    float sn, cs;
    sincosf(ang, &sn, &cs);
    rope[idx] = make_float2(cs, sn);
  } else {                                       // bias concat [1536]
    int idx = (b - 58) * 256 + tid;
    bqkv[idx] = idx < 512 ? bq[idx] : bkv[idx - 512];
  }
}

// ---------------- build_adj + fused QKV GEMM (rotary epilogue) ----------------
// grid 896: [0,128) edge blocks; [128,896) gemm 64x64 tiles: bm=(gb&31)*64, bn=(gb>>5)*64

__global__ __launch_bounds__(256) void qkv_adj(const int* __restrict__ ei,
    const int* __restrict__ node2c, const int* __restrict__ node2p,
    unsigned* __restrict__ adjb, int E,
    const bf16* __restrict__ A, const bf16* __restrict__ Bt, const float* __restrict__ bias,
    bf16* __restrict__ qbo, bf16* __restrict__ kbo, bf16* __restrict__ vbo,
    const float2* __restrict__ rope) {
  int b = blockIdx.x;
  if (b < 128) {
    int t = b * 256 + threadIdx.x;
    if (t < E) {
      int u = ei[t], v = ei[E + t];
      int cu = node2c[u];
      if (cu == node2c[v]) {
        int pu = node2p[u], pv = node2p[v];
        atomicOr(&adjb[(cu * 128 + pu) * 4 + (pv >> 5)], 1u << (pv & 31));
      }
    }
    return;
  }
  int gb = b - 128;
  const int Kd = CC;
  int bm = (gb & 31) * 64;
  int bn = (gb >> 5) * 64;
  int wave = threadIdx.x >> 6;
  int lane = threadIdx.x & 63;
  int wm = (wave & 1) * 32, wn = (wave >> 1) * 32;
  int lr = lane & 15;
  int lk = (lane >> 4) * 8;
  const bf16* pa0 = A + (size_t)(bm + wm + lr) * Kd + lk;
  const bf16* pa1 = pa0 + 16 * (size_t)Kd;
  const bf16* pb0 = Bt + (size_t)(bn + wn + lr) * Kd + lk;
  const bf16* pb1 = pb0 + 16 * (size_t)Kd;
  f32x4 acc00 = {0.f, 0.f, 0.f, 0.f}, acc01 = acc00, acc10 = acc00, acc11 = acc00;
  #pragma unroll 2
  for (int kb = 0; kb < Kd; kb += 32) {
    short8 a0 = *(const short8*)(pa0 + kb);
    short8 a1 = *(const short8*)(pa1 + kb);
    short8 b0 = *(const short8*)(pb0 + kb);
    short8 b1 = *(const short8*)(pb1 + kb);
    acc00 = __builtin_amdgcn_mfma_f32_16x16x32_bf16(a0, b0, acc00, 0, 0, 0);
    acc01 = __builtin_amdgcn_mfma_f32_16x16x32_bf16(a0, b1, acc01, 0, 0, 0);
    acc10 = __builtin_amdgcn_mfma_f32_16x16x32_bf16(a1, b0, acc10, 0, 0, 0);
    acc11 = __builtin_amdgcn_mfma_f32_16x16x32_bf16(a1, b1, acc11, 0, 0, 0);
  }
  int r0 = bm + wm + (lane >> 4) * 4;
  int c0 = bn + wn + lr;
  float bia0 = bias[c0];
  float bia1 = bias[c0 + 16];
  float vals[2][2][4];
  #pragma unroll
  for (int r = 0; r < 2; ++r) {
    #pragma unroll
    for (int c = 0; c < 2; ++c) {
      f32x4 av = (r == 0) ? (c == 0 ? acc00 : acc01) : (c == 0 ? acc10 : acc11);
      float bb = (c == 0) ? bia0 : bia1;
      #pragma unroll
      for (int i = 0; i < 4; ++i) vals[r][c][i] = av[i] + bb;
    }
  }
  int seg = c0 >> 9;  // block-uniform: 0=q, 1=k, 2=v
  if (seg == 2) {
    #pragma unroll
    for (int r = 0; r < 2; ++r)
      #pragma unroll
      for (int c = 0; c < 2; ++c)
        #pragma unroll
        for (int i = 0; i < 4; ++i)
          vbo[(size_t)(r0 + r * 16 + i) * 512 + (c0 - 1024 + 16 * c)] =
              __float2bfloat16(vals[r][c][i]);
  } else {
    bf16* dst = seg ? kbo : qbo;
    int colbase = c0 - seg * 512;
    #pragma unroll
    for (int r = 0; r < 2; ++r) {
      #pragma unroll
      for (int c = 0; c < 2; ++c) {
        int col = colbase + 16 * c;
        int tp = (col & 63) >> 1;
        bool odd = (col & 1) != 0;
        #pragma unroll
        for (int i = 0; i < 4; ++i) {
          int row = r0 + r * 16 + i;
          float v = vals[r][c][i];
          float p = __shfl_xor(v, 1, 64);          // partner col (col^1)
          float2 cssn = rope[(row & 127) * 32 + tp];
          float o = odd ? fmaf(v, cssn.x, p * cssn.y) : fmaf(v, cssn.x, -p * cssn.y);
          dst[(size_t)row * 512 + col] = __float2bfloat16(o);
        }
      }
    }
  }
}

// ---------------- MFMA attention: block = (cluster, head, q-half), 4 waves x 16 rows ------

__global__ __launch_bounds__(256) void attn_mfma(const bf16* __restrict__ qb,
    const bf16* __restrict__ kbg, const bf16* __restrict__ vbg,
    const unsigned* __restrict__ adjb, const float* __restrict__ e01,
    bf16* __restrict__ attn_o) {
  __shared__ short Kb[SS][72];
  __shared__ short Vt[DH][136];
  __shared__ short Psh[4][16][136];
  __shared__ unsigned adjsh[SS][4];
  __shared__ float e0sh[DH], e1sh[DH];

  int blk = blockIdx.x;
  int half = blk & 1, h = (blk >> 1) & 7, c = blk >> 4;
  int tid = threadIdx.x;
  int w = tid >> 6, l = tid & 63;
  int lg = l >> 4, lr = l & 15;

  // ---- staging ----
  {
    int j = tid & 127, hd = tid >> 7;
    const short8* ksrc = (const short8*)(kbg + ((size_t)(c * SS + j)) * INNER + h * DH + hd * 32);
    const short8* vsrc = (const short8*)(vbg + ((size_t)(c * SS + j)) * INNER + h * DH + hd * 32);
    #pragma unroll
    for (int ch = 0; ch < 4; ++ch) {
      *(short8*)&Kb[j][hd * 32 + ch * 8] = ksrc[ch];
      short8 vv = vsrc[ch];
      #pragma unroll
      for (int e = 0; e < 8; ++e) Vt[hd * 32 + ch * 8 + e][j] = vv[e];
    }
  }
  if (tid < 128) {
    *(uint4*)&adjsh[tid][0] = *(const uint4*)(adjb + (size_t)(c * SS + tid) * 4);
  } else if (tid < 192) {
    e0sh[tid - 128] = e01[h * DH + (tid - 128)];
  } else {
    e1sh[tid - 192] = e01[INNER + h * DH + (tid - 192)];
  }
  __syncthreads();

  int ib = half * 64 + w * 16;

  // ---- Q frags + qe dots (rows ib+lr) ----
  const bf16* qrow = qb + ((size_t)(c * SS + ib + lr)) * INNER + h * DH + lg * 8;
  short8 aq0 = *(const short8*)(qrow);
  short8 aq1 = *(const short8*)(qrow + 32);
  float d0 = 0.f, d1 = 0.f;
  #pragma unroll
  for (int e = 0; e < 8; ++e) {
    float q0 = bf2f(aq0[e]), q1 = bf2f(aq1[e]);
    d0 += q0 * e0sh[lg * 8 + e] + q1 * e0sh[lg * 8 + 32 + e];
    d1 += q0 * e1sh[lg * 8 + e] + q1 * e1sh[lg * 8 + 32 + e];
  }
  d0 += __shfl_xor(d0, 16, 64); d0 += __shfl_xor(d0, 32, 64);
  d1 += __shfl_xor(d1, 16, 64); d1 += __shfl_xor(d1, 32, 64);

  // ---- QK^T ----
  f32x4 sacc[8];
  #pragma unroll
  for (int n = 0; n < 8; ++n) sacc[n] = (f32x4){0.f, 0.f, 0.f, 0.f};
  #pragma unroll
  for (int n = 0; n < 8; ++n) {
    short8 bk0 = *(const short8*)&Kb[16 * n + lr][lg * 8];
    short8 bk1 = *(const short8*)&Kb[16 * n + lr][lg * 8 + 32];
    sacc[n] = __builtin_amdgcn_mfma_f32_16x16x32_bf16(aq0, bk0, sacc[n], 0, 0, 0);
    sacc[n] = __builtin_amdgcn_mfma_f32_16x16x32_bf16(aq1, bk1, sacc[n], 0, 0, 0);
  }

  // ---- softmax on C-layout ----
  unsigned aw[4][4];
  float qe0r[4], qe1r[4];
  #pragma unroll
  for (int ii = 0; ii < 4; ++ii) {
    int i = ib + lg * 4 + ii;
    #pragma unroll
    for (int t = 0; t < 4; ++t) aw[ii][t] = adjsh[i][t];
    qe0r[ii] = __shfl(d0, lg * 4 + ii, 64);
    qe1r[ii] = __shfl(d1, lg * 4 + ii, 64);
  }
  float rmax[4] = {-1e30f, -1e30f, -1e30f, -1e30f};
  #pragma unroll
  for (int n = 0; n < 8; ++n) {
    #pragma unroll
    for (int ii = 0; ii < 4; ++ii) {
      unsigned bit = (aw[ii][n >> 1] >> (((n & 1) << 4) + lr)) & 1u;
      float sv = (sacc[n][ii] + (bit ? qe1r[ii] : qe0r[ii])) * 0.125f;
      sacc[n][ii] = sv;
      rmax[ii] = fmaxf(rmax[ii], sv);
    }
  }
  #pragma unroll
  for (int o = 1; o <= 8; o <<= 1) {
    #pragma unroll
    for (int ii = 0; ii < 4; ++ii) rmax[ii] = fmaxf(rmax[ii], __shfl_xor(rmax[ii], o, 64));
  }
  float lsum[4] = {0.f, 0.f, 0.f, 0.f}, a1[4] = {0.f, 0.f, 0.f, 0.f};
  #pragma unroll
  for (int n = 0; n < 8; ++n) {
    #pragma unroll
    for (int ii = 0; ii < 4; ++ii) {
      unsigned bit = (aw[ii][n >> 1] >> (((n & 1) << 4) + lr)) & 1u;
      float pv = __expf(sacc[n][ii] - rmax[ii]);
      lsum[ii] += pv;
      if (bit) a1[ii] += pv;
      Psh[w][lg * 4 + ii][16 * n + lr] = f2bf(pv);
    }
  }
  #pragma unroll
  for (int o = 1; o <= 8; o <<= 1) {
    #pragma unroll
    for (int ii = 0; ii < 4; ++ii) {
      lsum[ii] += __shfl_xor(lsum[ii], o, 64);
      a1[ii]   += __shfl_xor(a1[ii], o, 64);
    }
  }

  // ---- PV ----
  f32x4 oacc[4];
  #pragma unroll
  for (int n = 0; n < 4; ++n) oacc[n] = (f32x4){0.f, 0.f, 0.f, 0.f};
  #pragma unroll
  for (int kb = 0; kb < 4; ++kb) {
    short8 pa = *(const short8*)&Psh[w][lr][kb * 32 + lg * 8];
    #pragma unroll
    for (int n = 0; n < 4; ++n) {
      short8 vb = *(const short8*)&Vt[16 * n + lr][kb * 32 + lg * 8];
      oacc[n] = __builtin_amdgcn_mfma_f32_16x16x32_bf16(pa, vb, oacc[n], 0, 0, 0);
    }
  }

  // ---- epilogue ----
  float e0r[4], e1r[4];
  #pragma unroll
  for (int n = 0; n < 4; ++n) { e0r[n] = e0sh[16 * n + lr]; e1r[n] = e1sh[16 * n + lr]; }
  #pragma unroll
  for (int ii = 0; ii < 4; ++ii) {
    float invl = 1.f / lsum[ii];
    float a1n = a1[ii] * invl;
    size_t row = (size_t)(c * SS + ib + lg * 4 + ii);
    #pragma unroll
    for (int n = 0; n < 4; ++n) {
      float val = oacc[n][ii] * invl + e0r[n] + a1n * (e1r[n] - e0r[n]);
      attn_o[row * INNER + h * DH + 16 * n + lr] = __float2bfloat16(val);
    }
  }
}

// ---------------- 32x64-tile MFMA GEMM, f32 out (Wo / W2 paths; N=256) ----------------
// grid (M/32, N/64), 4 waves: wave w -> rows 16*(w&1), cols 32*(w>>1). No LDS.

__global__ __launch_bounds__(256) void mfma_gemm32(const bf16* __restrict__ A,
    const bf16* __restrict__ Bt, const float* __restrict__ bias, float* __restrict__ C1,
    int Nd, int Kd) {
  int bm = blockIdx.x * 32;
  int bn = blockIdx.y * 64;
  int wave = threadIdx.x >> 6;
  int lane = threadIdx.x & 63;
  int wm = (wave & 1) * 16, wn = (wave >> 1) * 32;
  int lr = lane & 15;
  int lk = (lane >> 4) * 8;
  const bf16* pa0 = A + (size_t)(bm + wm + lr) * Kd + lk;
  const bf16* pb0 = Bt + (size_t)(bn + wn + lr) * Kd + lk;
  const bf16* pb1 = pb0 + 16 * (size_t)Kd;
  f32x4 acc0 = {0.f, 0.f, 0.f, 0.f}, acc1 = acc0;
  #pragma unroll 4
  for (int kb = 0; kb < Kd; kb += 32) {
    short8 a0 = *(const short8*)(pa0 + kb);
    short8 b0 = *(const short8*)(pb0 + kb);
    short8 b1 = *(const short8*)(pb1 + kb);
    acc0 = __builtin_amdgcn_mfma_f32_16x16x32_bf16(a0, b0, acc0, 0, 0, 0);
    acc1 = __builtin_amdgcn_mfma_f32_16x16x32_bf16(a0, b1, acc1, 0, 0, 0);
  }
  int r0 = bm + wm + (lane >> 4) * 4;
  int c0 = bn + wn + lr;
  float bia0 = bias[c0];
  float bia1 = bias[c0 + 16];
  #pragma unroll
  for (int i = 0; i < 4; ++i) {
    size_t row = (size_t)(r0 + i);
    C1[row * Nd + c0]      = acc0[i] + bia0;
    C1[row * Nd + c0 + 16] = acc1[i] + bia1;
  }
}

// ---------------- plain MFMA GEMM, gelu->bf16 epilogue (W1) ----------------

__global__ __launch_bounds__(256) void mfma_gemm_gelu(const bf16* __restrict__ A,
    const bf16* __restrict__ Bt, const float* __restrict__ bias, bf16* __restrict__ C1,
    int Nd, int Kd) {
  int bm = blockIdx.x * 64;
  int bn = blockIdx.y * 64;
  int wave = threadIdx.x >> 6;
  int lane = threadIdx.x & 63;
  int wm = (wave & 1) * 32, wn = (wave >> 1) * 32;
  int lr = lane & 15;
  int lk = (lane >> 4) * 8;
  const bf16* pa0 = A + (size_t)(bm + wm + lr) * Kd + lk;
  const bf16* pa1 = pa0 + 16 * (size_t)Kd;
  const bf16* pb0 = Bt + (size_t)(bn + wn + lr) * Kd + lk;
  const bf16* pb1 = pb0 + 16 * (size_t)Kd;
  f32x4 acc00 = {0.f, 0.f, 0.f, 0.f}, acc01 = acc00, acc10 = acc00, acc11 = acc00;
  #pragma unroll 2
  for (int kb = 0; kb < Kd; kb += 32) {
    short8 a0 = *(const short8*)(pa0 + kb);
    short8 a1 = *(const short8*)(pa1 + kb);
    short8 b0 = *(const short8*)(pb0 + kb);
    short8 b1 = *(const short8*)(pb1 + kb);
    acc00 = __builtin_amdgcn_mfma_f32_16x16x32_bf16(a0, b0, acc00, 0, 0, 0);
    acc01 = __builtin_amdgcn_mfma_f32_16x16x32_bf16(a0, b1, acc01, 0, 0, 0);
    acc10 = __builtin_amdgcn_mfma_f32_16x16x32_bf16(a1, b0, acc10, 0, 0, 0);
    acc11 = __builtin_amdgcn_mfma_f32_16x16x32_bf16(a1, b1, acc11, 0, 0, 0);
  }
  int r0 = bm + wm + (lane >> 4) * 4;
  int c0 = bn + wn + lr;
  float bia0 = bias[c0];
  float bia1 = bias[c0 + 16];
  #pragma unroll
  for (int r = 0; r < 2; ++r) {
    #pragma unroll
    for (int c = 0; c < 2; ++c) {
      f32x4 av = (r == 0) ? (c == 0 ? acc00 : acc01) : (c == 0 ? acc10 : acc11);
      float bb = (c == 0) ? bia0 : bia1;
      int col = c0 + c * 16;
      #pragma unroll
      for (int i = 0; i < 4; ++i) {
        float v = av[i] + bb;
        v = 0.5f * v * (1.f + erff(v * 0.70710678118654752f));
        C1[(size_t)(r0 + r * 16 + i) * Nd + col] = __float2bfloat16(v);
      }
    }
  }
}

// ---------------- gate1 + LN2 fused ----------------

__global__ __launch_bounds__(256) void gate1_ln2(const float* __restrict__ a,
    const float* __restrict__ x, const int* __restrict__ cl, const float* __restrict__ w,
    const float* __restrict__ g, const float* __restrict__ b,
    float* __restrict__ nodes1, bf16* __restrict__ h2) {
  __shared__ float red[8];
  int row = blockIdx.x;
  int c = threadIdx.x;
  float av = a[(size_t)row * CC + c];
  float rv = x[(size_t)cl[row] * CC + c];
  float contrib = av * w[c] + rv * w[CC + c] + (av - rv) * w[2 * CC + c];
  float t;
  block_reduce1(contrib, red, t);
  float gate = 1.f / (1.f + __expf(-t));
  float n1 = av * gate + rv * (1.f - gate);
  nodes1[(size_t)row * CC + c] = n1;
  float s, s2;
  block_reduce2(n1, n1 * n1, red, s, s2);
  float m = s * (1.f / CC);
  float var = s2 * (1.f / CC) - m * m;
  float r = rsqrtf(var + 1e-5f);
  h2[(size_t)row * CC + c] = __float2bfloat16((n1 - m) * r * g[c] + b[c]);
}

// ---------------- gate2 + final add fused ----------------

__global__ __launch_bounds__(256) void gate2_add(const float* __restrict__ a,
    const float* __restrict__ nodes1, const int* __restrict__ clusters,
    const float* __restrict__ w, const float* __restrict__ x, float* __restrict__ outp) {
  __shared__ float red[8];
  int row = blockIdx.x;
  int c = threadIdx.x;
  float av = a[(size_t)row * CC + c];
  float rv = nodes1[(size_t)row * CC + c];
  float contrib = av * w[c] + rv * w[CC + c] + (av - rv) * w[2 * CC + c];
  float t;
  block_reduce1(contrib, red, t);
  float gate = 1.f / (1.f + __expf(-t));
  float n2 = av * gate + rv * (1.f - gate);
  int node = clusters[row];
  outp[(size_t)node * CC + c] = x[(size_t)node * CC + c] + n2;
}

// ---------------- launch ----------------

extern "C" void kernel_launch(void* const* d_in, const int* in_sizes, int n_in,
                              void* d_out, int out_size, void* d_ws, size_t ws_size,
                              hipStream_t stream) {
  const float* x        = (const float*)d_in[0];
  const int*   edge_idx = (const int*)d_in[1];
  const int*   clusters = (const int*)d_in[2];
  const float* adj_emb  = (const float*)d_in[3];
  const float* ln1_g    = (const float*)d_in[4];
  const float* ln1_b    = (const float*)d_in[5];
  const float* Wq       = (const float*)d_in[6];
  const float* bq       = (const float*)d_in[7];
  const float* Wkv      = (const float*)d_in[8];
  const float* bkv      = (const float*)d_in[9];
  const float* We       = (const float*)d_in[10];
  const float* be       = (const float*)d_in[11];
  const float* Wo       = (const float*)d_in[12];
  const float* bo       = (const float*)d_in[13];
  const float* gate1_w  = (const float*)d_in[14];
  const float* ln2_g    = (const float*)d_in[15];
  const float* ln2_b    = (const float*)d_in[16];
  const float* W1       = (const float*)d_in[17];
  const float* b1       = (const float*)d_in[18];
  const float* W2       = (const float*)d_in[19];
  const float* b2       = (const float*)d_in[20];
  const float* gate2_w  = (const float*)d_in[21];
  float* out = (float*)d_out;

  char* ws = (char*)d_ws;
  int*      node2c = (int*)(ws + 0);            // 8KB
  int*      node2p = (int*)(ws + 8192);         // 8KB
  unsigned* adjb   = (unsigned*)(ws + 16384);   // 32KB [ws+16384, ws+49152)
  float*    e01    = (float*)(ws + 49152);      // 4KB
  float2*   rope   = (float2*)(ws + 53248);     // 32KB [128][32]
  float*    bqkv   = (float*)(ws + 86016);      // 6KB
  const size_t MB = 1ull << 20;
  char* w2 = ws + 131072;
  bf16*  h      = (bf16*) (w2 + 0 * MB);    // 1MB  [2048][256]
  bf16*  qb     = (bf16*) (w2 + 1 * MB);    // 2MB  [2048][512]
  bf16*  kbg    = (bf16*) (w2 + 3 * MB);    // 2MB
  bf16*  vbg    = (bf16*) (w2 + 5 * MB);    // 2MB
  bf16*  attn_o = (bf16*) (w2 + 7 * MB);    // 2MB
  float* proj   = (float*)(w2 + 9 * MB);    // 2MB
  float* nodes1 = (float*)(w2 + 11 * MB);   // 2MB
  bf16*  h2     = (bf16*) (w2 + 13 * MB);   // 1MB
  bf16*  ff1    = (bf16*) (w2 + 14 * MB);   // 4MB  [2048][1024]
  float* ff2    = (float*)(w2 + 18 * MB);   // 2MB
  bf16*  Wqkvt  = (bf16*) (w2 + 20 * MB);              // 768KB [1536][256]
  bf16*  Wot    = (bf16*) (w2 + 20 * MB + 768 * 1024); // 256KB [256][512]
  bf16*  W1t    = (bf16*) (w2 + 21 * MB);              // 512KB [1024][256]
  bf16*  W2t    = (bf16*) (w2 + 21 * MB + 512 * 1024); // 512KB [256][1024]
  if (ws_size < 131072 + 22 * MB) return;

  int E = in_sizes[1] / 2;

  prep_ln<<<2368, 256, 0, stream>>>(clusters, adj_emb, We, be, Wq, Wkv, Wo, W1, W2, bq, bkv,
                                    x, ln1_g, ln1_b,
                                    node2c, node2p, adjb, e01, rope, bqkv,
                                    Wqkvt, Wot, W1t, W2t, h);
  qkv_adj<<<896, 256, 0, stream>>>(edge_idx, node2c, node2p, adjb, E,
                                   h, Wqkvt, bqkv, qb, kbg, vbg, rope);
  attn_mfma<<<256, 256, 0, stream>>>(qb, kbg, vbg, adjb, e01, attn_o);
  mfma_gemm32<<<dim3(64, 4), 256, 0, stream>>>(attn_o, Wot, bo, proj, CC, INNER);
  gate1_ln2<<<NN, 256, 0, stream>>>(proj, x, clusters, gate1_w, ln2_g, ln2_b, nodes1, h2);
  mfma_gemm_gelu<<<dim3(32, 16), 256, 0, stream>>>(h2, W1t, b1, ff1, 4 * CC, CC);
  mfma_gemm32<<<dim3(64, 4), 256, 0, stream>>>(ff1, W2t, b2, ff2, CC, 4 * CC);
  gate2_add<<<NN, 256, 0, stream>>>(ff2, nodes1, clusters, gate2_w, x, out);
}